// Round 4
// baseline (317.770 us; speedup 1.0000x reference)
//
#include <hip/hip_runtime.h>

#define NN 100000
#define NE 200000
#define DN 128
#define DE 16
#define NR 3
#define NEDGE (NR * NE)         // 600000
#define NB1 98                  // scan1 blocks: 1024 elems each >= NN
#define NSTRIP 6250             // NN / 16 exactly
#define GEMM_GRID 1024

typedef __attribute__((ext_vector_type(8))) short short8;
typedef __attribute__((ext_vector_type(4))) float f32x4;

__device__ __forceinline__ unsigned short f2bf(float f) {
    unsigned int u = __float_as_uint(f);
    u = (u + 0x7fffu + ((u >> 16) & 1u)) >> 16;   // RNE
    return (unsigned short)u;
}

// ---------------------------------------------------------------------------
// prep: Wt[m][n][k] = bf16(W_m[k][n])            (ids 0..65535)
//       Wea[n][k]   = bf16(We_{k/16}[k%16][n])   (ids 65536..73727, k<48; 0 pad)
//       + dst histogram; records each edge's rank within its dst
//       (tmp[eid] = old count) so fill needs NO atomics.
// ---------------------------------------------------------------------------
__global__ __launch_bounds__(256) void prep_kernel(
    const float* __restrict__ W_self, const float* __restrict__ W_rel,
    const float* __restrict__ We,
    unsigned short* __restrict__ Wt, unsigned short* __restrict__ Wea,
    const int* __restrict__ ei, unsigned* __restrict__ cur,
    unsigned char* __restrict__ tmp)
{
    const int id = blockIdx.x * 256 + threadIdx.x;   // grid 1024*256 = 262144
    if (id < 65536) {
        const int m = id >> 14, rem = id & 16383;
        const int k = rem >> 7, n = rem & 127;
        const float* src = (m == 0) ? W_self : (W_rel + (size_t)(m - 1) * 16384);
        Wt[m * 16384 + n * 128 + k] = f2bf(src[k * 128 + n]);
    } else if (id < 65536 + 8192) {
        const int wid = id - 65536;
        const int n = wid >> 6, k = wid & 63;
        // Wea[n][k] = We[k>>4][k&15][n] for k<48, else 0
        const float v = (k < 48) ? We[(k >> 4) * 2048 + (k & 15) * 128 + n] : 0.f;
        Wea[n * 64 + k] = f2bf(v);
    }
    const int2* ei2 = (const int2*)ei;
    for (int eid = id; eid < NEDGE; eid += 262144) {
        const int2 e = ei2[eid];
        const unsigned pos = atomicAdd(&cur[e.y], 1u);
        tmp[eid] = (unsigned char)pos;   // max degree ~30 << 256
    }
}

// ---------------------------------------------------------------------------
// MFMA GEMM, persistent-B streaming: NO LDS, NO barriers.  (unchanged r3)
// ---------------------------------------------------------------------------
__global__ __launch_bounds__(256, 2) void gemm_kernel(
    const float* __restrict__ x,
    const unsigned short* __restrict__ Wt,
    unsigned short* __restrict__ zb,
    unsigned short* __restrict__ y)
{
    const int tid = threadIdx.x;
    const int m = tid >> 6;            // wave index == weight matrix index
    const int lane = tid & 63;
    const int lm = lane & 15;
    const int lq = lane >> 4;

    short8 bfr[8][4];
    {
        const unsigned short* wp = Wt + (size_t)m * 16384;
        #pragma unroll
        for (int cg = 0; cg < 8; ++cg)
            #pragma unroll
            for (int ks = 0; ks < 4; ++ks)
                bfr[cg][ks] = *(const short8*)(wp + (cg * 16 + lm) * 128 + ks * 32 + lq * 8);
    }
    unsigned short* outp = (m == 0) ? zb : (y + (size_t)(m - 1) * NN * 128);

    int s = blockIdx.x;
    float4 xb[8];
    {
        const float* xp = x + (size_t)(s * 16 + lm) * 128 + lq * 8;
        #pragma unroll
        for (int ks = 0; ks < 4; ++ks) {
            xb[2 * ks]     = *(const float4*)(xp + ks * 32);
            xb[2 * ks + 1] = *(const float4*)(xp + ks * 32 + 4);
        }
    }

    while (true) {
        short8 af[4];
        #pragma unroll
        for (int ks = 0; ks < 4; ++ks) {
            short8 t;
            t[0] = f2bf(xb[2 * ks].x);     t[1] = f2bf(xb[2 * ks].y);
            t[2] = f2bf(xb[2 * ks].z);     t[3] = f2bf(xb[2 * ks].w);
            t[4] = f2bf(xb[2 * ks + 1].x); t[5] = f2bf(xb[2 * ks + 1].y);
            t[6] = f2bf(xb[2 * ks + 1].z); t[7] = f2bf(xb[2 * ks + 1].w);
            af[ks] = t;
        }
        const int sn = s + GEMM_GRID;
        if (sn < NSTRIP) {
            const float* xp = x + (size_t)(sn * 16 + lm) * 128 + lq * 8;
            #pragma unroll
            for (int ks = 0; ks < 4; ++ks) {
                xb[2 * ks]     = *(const float4*)(xp + ks * 32);
                xb[2 * ks + 1] = *(const float4*)(xp + ks * 32 + 4);
            }
        }
        f32x4 acc[8];
        #pragma unroll
        for (int cg = 0; cg < 8; ++cg) acc[cg] = (f32x4){0.f, 0.f, 0.f, 0.f};
        #pragma unroll
        for (int cg = 0; cg < 8; ++cg)
            #pragma unroll
            for (int ks = 0; ks < 4; ++ks)
                acc[cg] = __builtin_amdgcn_mfma_f32_16x16x32_bf16(bfr[cg][ks], af[ks], acc[cg], 0, 0, 0);
        unsigned short* rp = outp + (size_t)(s * 16 + lm) * 128 + lq * 4;
        #pragma unroll
        for (int cg = 0; cg < 8; ++cg) {
            ushort4 o;
            o.x = f2bf(acc[cg][0]); o.y = f2bf(acc[cg][1]);
            o.z = f2bf(acc[cg][2]); o.w = f2bf(acc[cg][3]);
            *(ushort4*)(rp + cg * 16) = o;
        }
        if (sn >= NSTRIP) break;
        s = sn;
    }
}

// ---------------------------------------------------------------------------
// CSR build: scans (fill is atomic-free)
// ---------------------------------------------------------------------------
__global__ __launch_bounds__(256) void scan1_kernel(
    const unsigned* __restrict__ cnt, unsigned* __restrict__ offs,
    unsigned* __restrict__ bsum)
{
    __shared__ unsigned wtot[4];
    const int tid = threadIdx.x, lane = tid & 63, wv = tid >> 6;
    const int base = blockIdx.x * 1024 + tid * 4;
    unsigned c[4];
    #pragma unroll
    for (int j = 0; j < 4; ++j) c[j] = (base + j < NN) ? cnt[base + j] : 0u;
    const unsigned ts = c[0] + c[1] + c[2] + c[3];
    unsigned incl = ts;
    #pragma unroll
    for (int d = 1; d < 64; d <<= 1) {
        unsigned v = __shfl_up(incl, d, 64);
        if (lane >= d) incl += v;
    }
    if (lane == 63) wtot[wv] = incl;
    __syncthreads();
    unsigned woff = 0;
    for (int p = 0; p < 4; ++p) if (p < wv) woff += wtot[p];
    unsigned run = woff + incl - ts;
    #pragma unroll
    for (int j = 0; j < 4; ++j) {
        if (base + j < NN) offs[base + j] = run;
        run += c[j];
    }
    if (tid == 255) bsum[blockIdx.x] = woff + incl;
}

__global__ void scan2_kernel(unsigned* __restrict__ bsum)
{
    const int lane = threadIdx.x;   // 64
    unsigned v[2], s = 0;
    const int base = lane * 2;
    #pragma unroll
    for (int j = 0; j < 2; ++j) {
        v[j] = (base + j < NB1) ? bsum[base + j] : 0u;
        s += v[j];
    }
    unsigned incl = s;
    #pragma unroll
    for (int d = 1; d < 64; d <<= 1) {
        unsigned t = __shfl_up(incl, d, 64);
        if (lane >= d) incl += t;
    }
    unsigned run = incl - s;
    #pragma unroll
    for (int j = 0; j < 2; ++j) {
        if (base + j < NB1) bsum[base + j] = run;
        run += v[j];
    }
}

__global__ __launch_bounds__(256) void scan3_kernel(
    unsigned* __restrict__ offs, const unsigned* __restrict__ bsum)
{
    const int base = blockIdx.x * 1024 + threadIdx.x * 4;
    const unsigned add = bsum[blockIdx.x];
    #pragma unroll
    for (int j = 0; j < 4; ++j)
        if (base + j < NN) offs[base + j] += add;
    if (blockIdx.x == 0 && threadIdx.x == 0) offs[NN] = NEDGE;
}

__global__ __launch_bounds__(256) void fill_kernel(
    const int* __restrict__ ei, const unsigned* __restrict__ offs,
    const unsigned char* __restrict__ tmp,
    unsigned* __restrict__ erow, unsigned* __restrict__ eeid)
{
    const int eid = blockIdx.x * 256 + threadIdx.x;
    if (eid < NEDGE) {
        const int2 e = ((const int2*)ei)[eid];
        const unsigned r = (eid >= 2 * NE) ? 2u : (eid >= NE ? 1u : 0u);
        const unsigned pos = offs[e.y] + (unsigned)tmp[eid];
        erow[pos] = r * NN + (unsigned)e.x;   // y-row index (for aggregate)
        eeid[pos] = (unsigned)eid;            // edge id (for eaz)
    }
}

// ---------------------------------------------------------------------------
// eaz: per-dst edge_attr reduction + [16x48]@[48x128] MFMA, RMW into zb.
//   Block = 4 waves = 16 dsts. Phase A: wave reduces 4 dst segments; lane
//   (g=lane>>4, k=lane&15) accumulates ea_g[k] (g=3 lanes stay 0 = K pad).
//   Phase B: eaS[16][64] bf16 -> 2 ks MFMA per col-group (wave owns 2 cg),
//   zb[row] += result (block owns rows exclusively -> no race).
// ---------------------------------------------------------------------------
__global__ __launch_bounds__(256, 4) void eaz_kernel(
    const float* __restrict__ edge_attr,       // [NEDGE][16]
    const unsigned short* __restrict__ Wea,    // [128][64] bf16
    const unsigned* __restrict__ offs,
    const unsigned* __restrict__ eeid,
    unsigned short* __restrict__ zb)
{
    __shared__ __align__(16) unsigned short eaS[16][64];
    const int tid = threadIdx.x;
    const int wv = tid >> 6, lane = tid & 63;
    const int g = lane >> 4;          // rel group (3 = pad lanes)
    const int k16 = lane & 15;
    const int row0 = blockIdx.x * 16;

    #pragma unroll
    for (int d = 0; d < 4; ++d) {
        const int dst = row0 + wv * 4 + d;
        const unsigned s = __builtin_amdgcn_readfirstlane(offs[dst]);
        const unsigned e = __builtin_amdgcn_readfirstlane(offs[dst + 1]);
        float ea = 0.f;
        unsigned py[8];
        #pragma unroll
        for (int j = 0; j < 8; ++j) {
            const unsigned q = eeid[s + j];              // +8 pad allocated
            py[j] = (q < (unsigned)NEDGE) ? q : 0u;
        }
        float a[8];
        #pragma unroll
        for (int j = 0; j < 8; ++j)
            a[j] = edge_attr[(size_t)py[j] * 16 + k16];
        #pragma unroll
        for (int j = 0; j < 8; ++j) {
            const bool ok = ((s + (unsigned)j) < e)
                && py[j] >= (unsigned)(g * NE) && py[j] < (unsigned)((g + 1) * NE);
            ea += ok ? a[j] : 0.f;
        }
        for (unsigned i = s + 8; i < e; ++i) {
            const unsigned q = eeid[i];
            const float av = edge_attr[(size_t)q * 16 + k16];
            const bool ok = q >= (unsigned)(g * NE) && q < (unsigned)((g + 1) * NE);
            ea += ok ? av : 0.f;
        }
        eaS[wv * 4 + d][lane] = f2bf(ea);
    }
    __syncthreads();

    const int lm = lane & 15, lq = lane >> 4;
    const short8 af0 = *(const short8*)&eaS[lm][lq * 8];
    const short8 af1 = *(const short8*)&eaS[lm][32 + lq * 8];
    #pragma unroll
    for (int h = 0; h < 2; ++h) {
        const int cg = wv * 2 + h;
        const short8 b0 = *(const short8*)(Wea + (cg * 16 + lm) * 64 + lq * 8);
        const short8 b1 = *(const short8*)(Wea + (cg * 16 + lm) * 64 + 32 + lq * 8);
        f32x4 acc = {0.f, 0.f, 0.f, 0.f};
        acc = __builtin_amdgcn_mfma_f32_16x16x32_bf16(b0, af0, acc, 0, 0, 0);
        acc = __builtin_amdgcn_mfma_f32_16x16x32_bf16(b1, af1, acc, 0, 0, 0);
        unsigned short* zp = zb + (size_t)(row0 + lm) * 128 + cg * 16 + lq * 4;
        const ushort4 old = *(const ushort4*)zp;
        ushort4 o;
        o.x = f2bf(__uint_as_float((unsigned)old.x << 16) + acc[0]);
        o.y = f2bf(__uint_as_float((unsigned)old.y << 16) + acc[1]);
        o.z = f2bf(__uint_as_float((unsigned)old.z << 16) + acc[2]);
        o.w = f2bf(__uint_as_float((unsigned)old.w << 16) + acc[3]);
        *(ushort4*)zp = o;
    }
}

// ---------------------------------------------------------------------------
// Aggregate: pure y-gather + sum. NO LDS, NO edge_attr, NO epilogue matmul.
//   One wave = 4 dsts, 8 batched slots each (32 gathers in flight), serial
//   tail for deg>8. launch_bounds(256,4) -> 128 VGPR budget so the batch
//   arrays genuinely stay live (r3 failure: 52 VGPR = serialized phases).
// ---------------------------------------------------------------------------
__global__ __launch_bounds__(256, 4) void aggregate_kernel(
    const unsigned short* __restrict__ zb,
    const unsigned short* __restrict__ y,      // [3*NN][128] bf16
    const float* __restrict__ b,
    const unsigned* __restrict__ offs,         // [NN+1]
    const unsigned* __restrict__ erow,
    float* __restrict__ out)
{
    const int tid = threadIdx.x;
    const int wv = tid >> 6, lane = tid & 63;
    const int dst0 = (blockIdx.x * 4 + wv) * 4;   // grid 6250, exact
    const int col = 2 * lane;

    unsigned sI[4], eI[4];
    #pragma unroll
    for (int d = 0; d < 4; ++d) {
        sI[d] = __builtin_amdgcn_readfirstlane(offs[dst0 + d]);
        eI[d] = __builtin_amdgcn_readfirstlane(offs[dst0 + d + 1]);
    }

    unsigned r[4][8];
    #pragma unroll
    for (int d = 0; d < 4; ++d) {
        #pragma unroll
        for (int j = 0; j < 8; ++j) {
            const unsigned q = erow[sI[d] + j];          // +8 pad allocated
            r[d][j] = (q < 3u * NN) ? q : 0u;
        }
    }

    unsigned v[4][8];
    #pragma unroll
    for (int d = 0; d < 4; ++d)
        #pragma unroll
        for (int j = 0; j < 8; ++j)
            v[d][j] = *(const unsigned*)(y + (size_t)r[d][j] * 128 + col);

    float acc0[4], acc1[4];
    #pragma unroll
    for (int d = 0; d < 4; ++d) {
        const unsigned zv = *(const unsigned*)(zb + (size_t)(dst0 + d) * 128 + col);
        acc0[d] = __uint_as_float(zv << 16);
        acc1[d] = __uint_as_float(zv & 0xffff0000u);
    }

    #pragma unroll
    for (int d = 0; d < 4; ++d)
        #pragma unroll
        for (int j = 0; j < 8; ++j) {
            const unsigned vv = ((sI[d] + (unsigned)j) < eI[d]) ? v[d][j] : 0u;
            acc0[d] += __uint_as_float(vv << 16);
            acc1[d] += __uint_as_float(vv & 0xffff0000u);
        }

    #pragma unroll
    for (int d = 0; d < 4; ++d)
        for (unsigned i = sI[d] + 8; i < eI[d]; ++i) {
            const unsigned vv = *(const unsigned*)(y + (size_t)erow[i] * 128 + col);
            acc0[d] += __uint_as_float(vv << 16);
            acc1[d] += __uint_as_float(vv & 0xffff0000u);
        }

    const float2 bv = *(const float2*)(b + col);
    #pragma unroll
    for (int d = 0; d < 4; ++d) {
        float2 o;
        o.x = fmaxf(acc0[d] + bv.x, 0.f);
        o.y = fmaxf(acc1[d] + bv.y, 0.f);
        *(float2*)(out + (size_t)(dst0 + d) * 128 + col) = o;
    }
}

extern "C" void kernel_launch(void* const* d_in, const int* in_sizes, int n_in,
                              void* d_out, int out_size, void* d_ws, size_t ws_size,
                              hipStream_t stream)
{
    const float* x         = (const float*)d_in[0];
    const float* edge_attr = (const float*)d_in[1];
    const float* W_rel     = (const float*)d_in[2];
    const float* We_rel    = (const float*)d_in[3];
    const float* W_self    = (const float*)d_in[4];
    const float* b         = (const float*)d_in[5];
    const int*   edge_index= (const int*)d_in[6];
    float* out = (float*)d_out;

    // ws layout (bytes)
    char* wsb = (char*)d_ws;
    unsigned short* zb   = (unsigned short*)wsb;                     //  25,600,000
    unsigned short* y    = (unsigned short*)(wsb + 25600000);        //  76,800,000
    unsigned short* Wt   = (unsigned short*)(wsb + 102400000);       //     131,072
    unsigned short* Wea  = (unsigned short*)(wsb + 102531072);       //      16,384
    unsigned*       cur  = (unsigned*)(wsb + 102547456);             //     400,000
    unsigned*       offs = (unsigned*)(wsb + 102947456);             //     400,004
    unsigned*       bsum = (unsigned*)(wsb + 103347460);             //         512
    unsigned*       erow = (unsigned*)(wsb + 103347972);             //   2,400,032 (+8 pad)
    unsigned*       eeid = (unsigned*)(wsb + 105748004);             //   2,400,032 (+8 pad)
    unsigned char*  tmp  = (unsigned char*)(wsb + 108148036);        //     600,000

    hipMemsetAsync(cur, 0, NN * sizeof(unsigned), stream);
    prep_kernel<<<1024, 256, 0, stream>>>(W_self, W_rel, We_rel, Wt, Wea,
                                          edge_index, cur, tmp);
    gemm_kernel<<<GEMM_GRID, 256, 0, stream>>>(x, Wt, zb, y);

    scan1_kernel<<<NB1, 256, 0, stream>>>(cur, offs, bsum);
    scan2_kernel<<<1, 64, 0, stream>>>(bsum);
    scan3_kernel<<<NB1, 256, 0, stream>>>(offs, bsum);
    const int eblocks = (NEDGE + 255) / 256;
    fill_kernel <<<eblocks, 256, 0, stream>>>(edge_index, offs, tmp, erow, eeid);

    eaz_kernel<<<NN / 16, 256, 0, stream>>>(edge_attr, Wea, offs, eeid, zb);
    aggregate_kernel<<<NN / 16, 256, 0, stream>>>(zb, y, b, offs, erow, out);
}